// Round 1
// 270.740 us; speedup vs baseline: 1.0122x; 1.0122x over previous
//
#include <hip/hip_runtime.h>
#include <hip/hip_bf16.h>
#include <math.h>

#define BATCH 8
#define NATOMS 192
#define HF 32

using short8 = __attribute__((ext_vector_type(8))) short;
using f32x4  = __attribute__((ext_vector_type(4))) float;

__device__ __forceinline__ float fast_rcp(float x){ return __builtin_amdgcn_rcpf(x); }
__device__ __forceinline__ float sigmoid_f(float x){ return fast_rcp(1.0f+__expf(-x)); }
__device__ __forceinline__ float silu_f(float x){ return x*fast_rcp(1.0f+__expf(-x)); }
__device__ __forceinline__ float softplus_f(float x){ return fmaxf(x,0.0f)+log1pf(expf(-fabsf(x))); }
__device__ __forceinline__ unsigned short f2bf(float x){
  __hip_bfloat16 h = __float2bfloat16(x);
  return __builtin_bit_cast(unsigned short, h);
}

__device__ __forceinline__ float wave_sum(float v){
  v += __shfl_xor(v, 1);
  v += __shfl_xor(v, 2);
  v += __shfl_xor(v, 4);
  v += __shfl_xor(v, 8);
  v += __shfl_xor(v, 16);
  v += __shfl_xor(v, 32);
  return v;
}

// ---------------- prelude: 0..79 pdf dot; 80..87 gamma(b); 88..103 wprep ----
__global__ __launch_bounds__(256) void k_prelude(
    const float* __restrict__ pdf, const float* __restrict__ t,
    const float* __restrict__ pdf_w, const float* __restrict__ pdf_b,
    const float* __restrict__ g1w, const float* __restrict__ g1b,
    const float* __restrict__ g2w, const float* __restrict__ g2b,
    const float* __restrict__ g3w, const float* __restrict__ g3b,
    const float* __restrict__ gamma0, const float* __restrict__ gamma1,
    const float* __restrict__ e2w, const float* __restrict__ c2w,
    float* __restrict__ temb, float* __restrict__ pdfe,
    unsigned short* __restrict__ e2wb, unsigned short* __restrict__ c2wb)
{
  __shared__ float lds[4];
  const int bx = blockIdx.x, tid = threadIdx.x;
  const int wv = tid >> 6, ln = tid & 63;

  if (bx >= 88){                          // weight prep: bf16 cast of e2/c2
    const int g = (bx - 88)*256 + tid;    // 16*256 = 4096 = 4 layers * 32*32
    e2wb[g] = f2bf(e2w[g]);
    c2wb[g] = f2bf(c2w[g]);
    return;
  }
  if (bx < 80){
    const int b = bx / 10, o = bx % 10;
    const float* pb = pdf + b*3000;
    const float* wb = pdf_w + o*3000;
    float p = 0.f;
    for (int k = tid; k < 3000; k += 256) p = fmaf(pb[k], wb[k], p);
    p = wave_sum(p);
    if (ln == 0) lds[wv] = p;
    __syncthreads();
    if (tid == 0) pdfe[b*10 + o] = lds[0] + lds[1] + lds[2] + lds[3] + pdf_b[o];
    return;
  }
  const int b = bx - 80;
  const float w1 = softplus_f(g1w[0]);
  const float b1 = g1b[0];
  const float tn = t[b] * (1.0f/1000.0f);
  const float l1_0 = b1;
  const float l1_1 = w1 + b1;
  const float l1_t = fmaf(w1, tn, b1);
  float a0 = 0.f, a1 = 0.f, at = 0.f;
  for (int k = tid; k < 1024; k += 256){
    float w2 = softplus_f(g2w[k]);
    float bb = g2b[k];
    float w3 = softplus_f(g3w[k]);
    a0 += sigmoid_f(fmaf(w2, l1_0, bb)) * w3;
    a1 += sigmoid_f(fmaf(w2, l1_1, bb)) * w3;
    at += sigmoid_f(fmaf(w2, l1_t, bb)) * w3;
  }
  float sums[3]; float vals[3] = {a0, a1, at};
  for (int r = 0; r < 3; ++r){
    float v = wave_sum(vals[r]);
    __syncthreads();
    if (ln == 0) lds[wv] = v;
    __syncthreads();
    sums[r] = lds[0] + lds[1] + lds[2] + lds[3];
  }
  if (tid == 0){
    const float b3 = g3b[0];
    const float g0 = l1_0 + sums[0] + b3;
    const float g1v = l1_1 + sums[1] + b3;
    const float gt = l1_t + sums[2] + b3;
    temb[b] = gamma0[0] + (gamma1[0] - gamma0[0]) * (gt - g0) / (g1v - g0);
  }
}

// ---------------- embed + layer-0 node precompute (fused) -------------------
__global__ __launch_bounds__(256) void k_embed_node(
    const float* __restrict__ xyz, const float* __restrict__ temb,
    const float* __restrict__ pdfe,
    const float* __restrict__ wi, const float* __restrict__ bi,
    const float* __restrict__ lnhg, const float* __restrict__ lnhb,
    const float* __restrict__ e1w, const float* __restrict__ e1b,
    const float* __restrict__ c1w, const float* __restrict__ c1b,
    float* __restrict__ x, float* __restrict__ hln,
    float* __restrict__ ue, float* __restrict__ uc,
    float* __restrict__ vep, float* __restrict__ vcp)
{
  __shared__ float s_h[8][33];
  const int tid = threadIdx.x;
  const int il = tid >> 5, f = tid & 31;
  const int node = blockIdx.x*8 + il;
  const int b = node / NATOMS;
  const float* w = wi + f*12;
  float a = bi[f];
  a = fmaf(xyz[node*4 + 3], w[0], a);
  a = fmaf(temb[b], w[1], a);
  const float* pe = pdfe + b*10;
#pragma unroll
  for (int p = 0; p < 10; ++p) a = fmaf(pe[p], w[2+p], a);
  s_h[il][f] = a;
  if (f < 3) x[node*3 + f] = xyz[node*4 + f];
  __syncthreads();

  float hl[32];
  float m = 0.f;
#pragma unroll
  for (int k = 0; k < 32; ++k){ hl[k] = s_h[il][k]; m += hl[k]; }
  m *= (1.0f/32.0f);
  float v = 0.f;
#pragma unroll
  for (int k = 0; k < 32; ++k){ float d = hl[k]-m; v = fmaf(d, d, v); }
  float r = rsqrtf(v*(1.0f/32.0f) + 1e-5f);
#pragma unroll
  for (int k = 0; k < 32; ++k) hl[k] = fmaf((hl[k]-m)*r, lnhg[k], lnhb[k]);
  hln[node*32 + f] = hl[f];

  const float* we = e1w + f*66;
  float sv = e1b[f], su = 0.f;
#pragma unroll
  for (int k = 0; k < 32; ++k){ sv = fmaf(hl[k], we[k], sv); su = fmaf(hl[k], we[32+k], su); }
  vep[node*32 + f] = sv;
  ue [node*32 + f] = su;

  const float* wc = c1w + f*66;
  float cv = c1b[f], cu = 0.f;
#pragma unroll
  for (int k = 0; k < 32; ++k){ cv = fmaf(hl[k], wc[k], cv); cu = fmaf(hl[k], wc[32+k], cu); }
  vcp[node*32 + f] = cv;
  uc [node*32 + f] = cu;
}

// ---------------- fused per-layer kernel: pair (3 chunks) + post + heads ----
// Block (i,b), 128 threads. Phase 0: geometry for all 192 j + bf16 weight
// stage. Chunk loop c=0..2: phase1 m1/c1 -> bf16 LDS, phase2 wave0=edge
// (MFMA + gate + m_agg accum), wave1=cor (MFMA + xc accum). Then post:
// wave0 = node MLP + h-LN + e1-precompute (or h head when last),
// wave1 = x-LN + x update + c1-precompute (or x head when last).
// MFMA C layout: f=lane&15(+16*ft), j=jt*16+quad*4+reg [m89/m91].
__global__ __launch_bounds__(128, 3) void k_layer(
    const float* __restrict__ xin, const float* __restrict__ xyz,
    const float* __restrict__ ue, const float* __restrict__ uc,
    const float* __restrict__ vep, const float* __restrict__ vcp,
    const float* __restrict__ hln,
    const float* __restrict__ e1w, const float* __restrict__ c1w,
    const unsigned short* __restrict__ e2wb, const unsigned short* __restrict__ c2wb,
    const float* __restrict__ e2b, const float* __restrict__ eiw,
    const float* __restrict__ eib,
    const float* __restrict__ c2b, const float* __restrict__ c3w,
    const float* __restrict__ c3b,
    const float* __restrict__ n1w, const float* __restrict__ n1b,
    const float* __restrict__ n2w, const float* __restrict__ n2b,
    const float* __restrict__ lnxg, const float* __restrict__ lnxb,
    const float* __restrict__ lnhg_n, const float* __restrict__ lnhb_n,
    const float* __restrict__ e1w_n, const float* __restrict__ e1b_n,
    const float* __restrict__ c1w_n, const float* __restrict__ c1b_n,
    float* __restrict__ xout, float* __restrict__ hln_n,
    float* __restrict__ ue_n, float* __restrict__ uc_n,
    float* __restrict__ vep_n, float* __restrict__ vcp_n,
    const float* __restrict__ how, const float* __restrict__ hob,
    const float* __restrict__ xow, const float* __restrict__ xob,
    float* __restrict__ out, int last)
{
  __shared__ float s_geo[192][6];             // dfx,dfy,dfz,d2,d0,dist
  __shared__ unsigned short s_m1[64][40];     // bf16 m1 for current chunk
  __shared__ unsigned short s_c1[64][40];
  __shared__ unsigned short s_we[32][40];     // bf16 e2 weights [f][k]
  __shared__ unsigned short s_wc[32][40];
  __shared__ float s_mg[32];                  // m_agg
  __shared__ float s_hv[32];                  // hln row of node i
  __shared__ float s_n1[32];
  __shared__ float s_hl[32];                  // next-layer LN'd h

  const int i = blockIdx.x, b = blockIdx.y;
  const int tid = threadIdx.x;
  const int base = b * NATOMS;

  // ---- phase 0: all-192 geometry + weight staging ----
  {
    const float* xi_p = xin + (size_t)(base + i)*3;
    const float xi0 = xi_p[0], xi1 = xi_p[1], xi2 = xi_p[2];
    const float* x0i = xyz + (size_t)(base + i)*4;
    const float q0i = x0i[0], q1i = x0i[1], q2i = x0i[2];
    for (int j = tid; j < NATOMS; j += 128){
      const float* xj_p = xin + (size_t)(base + j)*3;
      const float dfx = xi0 - xj_p[0], dfy = xi1 - xj_p[1], dfz = xi2 - xj_p[2];
      const float d2 = dfx*dfx + dfy*dfy + dfz*dfz;
      const float dist = sqrtf(fmaxf(d2, 1e-12f));
      const float* x0j = xyz + (size_t)(base + j)*4;
      const float q0 = q0i - x0j[0], q1 = q1i - x0j[1], q2 = q2i - x0j[2];
      const float d0 = sqrtf(fmaxf(q0*q0 + q1*q1 + q2*q2, 1e-12f));
      s_geo[j][0] = dfx; s_geo[j][1] = dfy; s_geo[j][2] = dfz;
      s_geo[j][3] = d2;  s_geo[j][4] = d0;  s_geo[j][5] = dist;
    }
    const short8* es = (const short8*)e2wb;   // 128 chunks of 8 bf16
    const short8* cs = (const short8*)c2wb;
    const int f = tid >> 2, kq = tid & 3;
    *(short8*)&s_we[f][kq*8] = es[tid];
    *(short8*)&s_wc[f][kq*8] = cs[tid];
  }
  __syncthreads();

  // ---- loop-invariant setup ----
  const int kk = tid & 31, jg = tid >> 5;
  const float vpe = vep[(size_t)(base + i)*32 + kk];
  const float vpc = vcp[(size_t)(base + i)*32 + kk];
  const float we64 = e1w[kk*66 + 64], we65 = e1w[kk*66 + 65];
  const float wc64 = c1w[kk*66 + 64], wc65 = c1w[kk*66 + 65];

  const int lane = tid & 63, wv = tid >> 6;
  const int n = lane & 15, quad = lane >> 4;
  short8 wb0, wb1;
  float p0s, p1s, p2s, p3s, p4s;
  if (wv == 0){
    wb0 = *(const short8*)&s_we[n][quad*8];
    wb1 = *(const short8*)&s_we[16 + n][quad*8];
    p0s = e2b[n]; p1s = e2b[16 + n]; p2s = eiw[n]; p3s = eiw[16 + n]; p4s = eib[0];
  } else {
    wb0 = *(const short8*)&s_wc[n][quad*8];
    wb1 = *(const short8*)&s_wc[16 + n][quad*8];
    p0s = c2b[n]; p1s = c2b[16 + n]; p2s = c3w[n]; p3s = c3w[16 + n]; p4s = c3b[0];
  }
  float ma0 = 0.f, ma1 = 0.f;
  float px = 0.f, py = 0.f, pz = 0.f;

  // ---- chunk loop ----
  for (int c = 0; c < 3; ++c){
    // phase 1: m1/c1 fp32 -> bf16 LDS for this chunk
#pragma unroll
    for (int jj = jg; jj < 64; jj += 4){
      const int j = c*64 + jj;
      const float d2 = s_geo[j][3], d0 = s_geo[j][4];
      const float uev = ue[(size_t)(base + j)*32 + kk];
      s_m1[jj][kk] = f2bf(silu_f(fmaf(d2, we64, fmaf(d0, we65, vpe + uev))));
      const float ucv = uc[(size_t)(base + j)*32 + kk];
      s_c1[jj][kk] = f2bf(silu_f(fmaf(d2, wc64, fmaf(d0, wc65, vpc + ucv))));
    }
    __syncthreads();

    // phase 2
    if (wv == 0){
      // ======== edge wave ========
#pragma unroll
      for (int jt = 0; jt < 4; ++jt){
        short8 a = *(const short8*)&s_m1[jt*16 + n][quad*8];
        f32x4 z = {0.f, 0.f, 0.f, 0.f};
        f32x4 A0 = __builtin_amdgcn_mfma_f32_16x16x32_bf16(a, wb0, z, 0, 0, 0);
        f32x4 A1 = __builtin_amdgcn_mfma_f32_16x16x32_bf16(a, wb1, z, 0, 0, 0);
        float m20[4], m21[4], g[4];
#pragma unroll
        for (int r = 0; r < 4; ++r){
          m20[r] = silu_f(A0[r] + p0s);
          m21[r] = silu_f(A1[r] + p1s);
          g[r] = m20[r]*p2s + m21[r]*p3s;
        }
#pragma unroll
        for (int r = 0; r < 4; ++r){
          g[r] += __shfl_xor(g[r], 1);
          g[r] += __shfl_xor(g[r], 2);
          g[r] += __shfl_xor(g[r], 4);
          g[r] += __shfl_xor(g[r], 8);
        }
#pragma unroll
        for (int r = 0; r < 4; ++r){
          const int jglob = c*64 + jt*16 + quad*4 + r;
          const float e = (jglob == i) ? 0.0f : sigmoid_f(g[r] + p4s);
          ma0 = fmaf(e, m20[r], ma0);
          ma1 = fmaf(e, m21[r], ma1);
        }
      }
    } else {
      // ======== coordinate wave ========
#pragma unroll
      for (int jt = 0; jt < 4; ++jt){
        short8 a = *(const short8*)&s_c1[jt*16 + n][quad*8];
        f32x4 z = {0.f, 0.f, 0.f, 0.f};
        f32x4 A0 = __builtin_amdgcn_mfma_f32_16x16x32_bf16(a, wb0, z, 0, 0, 0);
        f32x4 A1 = __builtin_amdgcn_mfma_f32_16x16x32_bf16(a, wb1, z, 0, 0, 0);
        float g[4];
#pragma unroll
        for (int r = 0; r < 4; ++r)
          g[r] = silu_f(A0[r] + p0s)*p2s + silu_f(A1[r] + p1s)*p3s;
#pragma unroll
        for (int r = 0; r < 4; ++r){
          g[r] += __shfl_xor(g[r], 1);
          g[r] += __shfl_xor(g[r], 2);
          g[r] += __shfl_xor(g[r], 4);
          g[r] += __shfl_xor(g[r], 8);
        }
#pragma unroll
        for (int r = 0; r < 4; ++r){
          const int jgeo = c*64 + jt*16 + quad*4 + r;
          const float s = (g[r] + p4s) * fast_rcp(s_geo[jgeo][5] + 1.0f);
          px = fmaf(s, s_geo[jgeo][0], px);
          py = fmaf(s, s_geo[jgeo][1], py);
          pz = fmaf(s, s_geo[jgeo][2], pz);
        }
      }
    }
    __syncthreads();   // protect s_m1/s_c1 for next chunk
  }

  // ---- post phase ----
  if (wv == 0){
    ma0 += __shfl_xor(ma0, 16); ma0 += __shfl_xor(ma0, 32);
    ma1 += __shfl_xor(ma1, 16); ma1 += __shfl_xor(ma1, 32);
    if (lane < 16){ s_mg[lane] = ma0; s_mg[16 + lane] = ma1; }
  } else {
    px += __shfl_xor(px, 16); px += __shfl_xor(px, 32);
    py += __shfl_xor(py, 16); py += __shfl_xor(py, 32);
    pz += __shfl_xor(pz, 16); pz += __shfl_xor(pz, 32);
    if (lane < 32) s_hv[lane] = hln[(size_t)(base + i)*32 + lane];
  }
  __syncthreads();

  if (wv == 0){
    if (lane < 32){
      const int f = lane;
      float a = n1b[f];
      const float* w1 = n1w + f*64;
#pragma unroll
      for (int k = 0; k < 32; ++k) a = fmaf(s_hv[k], w1[k], a);
#pragma unroll
      for (int k = 0; k < 32; ++k) a = fmaf(s_mg[k], w1[32+k], a);
      s_n1[f] = silu_f(a);
    }
  } else {
    // x-path: every wave-1 lane holds the full px/py/pz totals
    const float* xr = xin + (size_t)(base + i)*3;
    const float x0 = xr[0], x1 = xr[1], x2 = xr[2];
    const float mx = (x0 + x1 + x2) * (1.0f/3.0f);
    const float v0 = x0-mx, v1 = x1-mx, v2 = x2-mx;
    const float r = rsqrtf((v0*v0 + v1*v1 + v2*v2)*(1.0f/3.0f) + 1e-5f);
    const float xn0 = fmaf((x0 - mx)*r, lnxg[0], lnxb[0]) + px;
    const float xn1 = fmaf((x1 - mx)*r, lnxg[1], lnxb[1]) + py;
    const float xn2 = fmaf((x2 - mx)*r, lnxg[2], lnxb[2]) + pz;
    if (!last){
      if (lane == 0){
        float* xo = xout + (size_t)(base + i)*3;
        xo[0] = xn0; xo[1] = xn1; xo[2] = xn2;
      }
    } else if (lane < 3){
      float o = xob[lane];
      o = fmaf(xn0, xow[lane*3 + 0], o);
      o = fmaf(xn1, xow[lane*3 + 1], o);
      o = fmaf(xn2, xow[lane*3 + 2], o);
      out[(size_t)(base + i)*4 + lane] = o - xyz[(size_t)(base + i)*4 + lane];
    }
  }
  __syncthreads();

  if (wv == 0 && lane < 32){
    const int f = lane;
    float o = n2b[f];
    const float* w2 = n2w + f*32;
#pragma unroll
    for (int k = 0; k < 32; ++k) o = fmaf(s_n1[k], w2[k], o);
    const float ho = s_hv[f] + o;
    if (last){
      float hp = ho * how[f];
      hp += __shfl_xor(hp, 1); hp += __shfl_xor(hp, 2);
      hp += __shfl_xor(hp, 4); hp += __shfl_xor(hp, 8);
      hp += __shfl_xor(hp, 16);
      if (f == 0) out[(size_t)(base + i)*4 + 3] = hp + hob[0];
    } else {
      float m = ho;
      m += __shfl_xor(m, 1); m += __shfl_xor(m, 2);
      m += __shfl_xor(m, 4); m += __shfl_xor(m, 8);
      m += __shfl_xor(m, 16);
      m *= (1.0f/32.0f);
      const float d = ho - m;
      float v = d*d;
      v += __shfl_xor(v, 1); v += __shfl_xor(v, 2);
      v += __shfl_xor(v, 4); v += __shfl_xor(v, 8);
      v += __shfl_xor(v, 16);
      const float r = rsqrtf(v*(1.0f/32.0f) + 1e-5f);
      const float hlv = fmaf(d*r, lnhg_n[f], lnhb_n[f]);
      s_hl[f] = hlv;
      hln_n[(size_t)(base + i)*32 + f] = hlv;
    }
  }
  if (!last){
    __syncthreads();
    if (lane < 32){
      const int f = lane;
      if (wv == 0){
        const float* we = e1w_n + f*66;
        float sv = e1b_n[f], su = 0.f;
#pragma unroll
        for (int k = 0; k < 32; ++k){ sv = fmaf(s_hl[k], we[k], sv); su = fmaf(s_hl[k], we[32+k], su); }
        vep_n[(size_t)(base + i)*32 + f] = sv;
        ue_n [(size_t)(base + i)*32 + f] = su;
      } else {
        const float* wc = c1w_n + f*66;
        float cv = c1b_n[f], cu = 0.f;
#pragma unroll
        for (int k = 0; k < 32; ++k){ cv = fmaf(s_hl[k], wc[k], cv); cu = fmaf(s_hl[k], wc[32+k], cu); }
        vcp_n[(size_t)(base + i)*32 + f] = cv;
        uc_n [(size_t)(base + i)*32 + f] = cu;
      }
    }
  }
}

extern "C" void kernel_launch(void* const* d_in, const int* in_sizes, int n_in,
                              void* d_out, int out_size, void* d_ws, size_t ws_size,
                              hipStream_t stream)
{
  const float* xyz      = (const float*)d_in[0];
  const float* pdf      = (const float*)d_in[1];
  const float* t        = (const float*)d_in[2];
  const float* emb_in_w = (const float*)d_in[3];
  const float* emb_in_b = (const float*)d_in[4];
  const float* emb_out_w= (const float*)d_in[5];
  const float* emb_out_b= (const float*)d_in[6];
  const float* x_out_w  = (const float*)d_in[7];
  const float* x_out_b  = (const float*)d_in[8];
  const float* pdf_w    = (const float*)d_in[9];
  const float* pdf_b    = (const float*)d_in[10];
  const float* g1w      = (const float*)d_in[11];
  const float* g1b      = (const float*)d_in[12];
  const float* g2w      = (const float*)d_in[13];
  const float* g2b      = (const float*)d_in[14];
  const float* g3w      = (const float*)d_in[15];
  const float* g3b      = (const float*)d_in[16];
  const float* gamma0   = (const float*)d_in[17];
  const float* gamma1   = (const float*)d_in[18];
  const float* lnhg     = (const float*)d_in[19];
  const float* lnhb     = (const float*)d_in[20];
  const float* lnxg     = (const float*)d_in[21];
  const float* lnxb     = (const float*)d_in[22];
  const float* e1w      = (const float*)d_in[23];
  const float* e1b      = (const float*)d_in[24];
  const float* e2w      = (const float*)d_in[25];
  const float* e2b      = (const float*)d_in[26];
  const float* eiw      = (const float*)d_in[27];
  const float* eib      = (const float*)d_in[28];
  const float* n1w      = (const float*)d_in[29];
  const float* n1b      = (const float*)d_in[30];
  const float* n2w      = (const float*)d_in[31];
  const float* n2b      = (const float*)d_in[32];
  const float* c1w      = (const float*)d_in[33];
  const float* c1b      = (const float*)d_in[34];
  const float* c2w      = (const float*)d_in[35];
  const float* c2b      = (const float*)d_in[36];
  const float* c3w      = (const float*)d_in[37];
  const float* c3b      = (const float*)d_in[38];

  const int NTOT = BATCH*NATOMS;          // 1536 nodes
  float* ws   = (float*)d_ws;
  float* temb = ws;                        // 8
  float* pdfe = ws + 8;                    // 80 (pad to 96)
  unsigned short* e2wb = (unsigned short*)(ws + 96);    // 4096 ushort
  unsigned short* c2wb = e2wb + 4096;                   // 4096 ushort
  float* p    = ws + 96 + 4096;            // (8192 ushort = 4096 floats)
  float* hln0 = p; p += NTOT*32;
  float* hln1 = p; p += NTOT*32;
  float* ue0  = p; p += NTOT*32;
  float* uc0  = p; p += NTOT*32;
  float* vep0 = p; p += NTOT*32;
  float* vcp0 = p; p += NTOT*32;
  float* ue1  = p; p += NTOT*32;
  float* uc1  = p; p += NTOT*32;
  float* vep1 = p; p += NTOT*32;
  float* vcp1 = p; p += NTOT*32;
  float* xb0  = p; p += NTOT*3;
  float* xb1  = p; p += NTOT*3;

  k_prelude<<<104, 256, 0, stream>>>(pdf, t, pdf_w, pdf_b,
      g1w, g1b, g2w, g2b, g3w, g3b, gamma0, gamma1,
      e2w, c2w, temb, pdfe, e2wb, c2wb);
  k_embed_node<<<NTOT/8, 256, 0, stream>>>(
      xyz, temb, pdfe, emb_in_w, emb_in_b,
      lnhg, lnhb, e1w, e1b, c1w, c1b,
      xb0, hln0, ue0, uc0, vep0, vcp0);

  float* hlnC = hln0; float* hlnN = hln1;
  float* ueC = ue0, *ucC = uc0, *vepC = vep0, *vcpC = vcp0;
  float* ueN = ue1, *ucN = uc1, *vepN = vep1, *vcpN = vcp1;
  float* xcur = xb0; float* xnext = xb1;

  for (int l = 0; l < 4; ++l){
    const int n = (l < 3) ? (l + 1) : 3;   // next-layer weights for precompute
    k_layer<<<dim3(NATOMS, BATCH), 128, 0, stream>>>(
        xcur, xyz, ueC, ucC, vepC, vcpC, hlnC,
        e1w + l*2112, c1w + l*2112,
        e2wb + l*1024, c2wb + l*1024,
        e2b + l*32, eiw + l*32, eib + l,
        c2b + l*32, c3w + l*32, c3b + l,
        n1w + l*2048, n1b + l*32, n2w + l*1024, n2b + l*32,
        lnxg + l*3, lnxb + l*3,
        lnhg + n*32, lnhb + n*32, e1w + n*2112, e1b + n*32,
        c1w + n*2112, c1b + n*32,
        xnext, hlnN, ueN, ucN, vepN, vcpN,
        emb_out_w, emb_out_b, x_out_w, x_out_b, (float*)d_out,
        (l == 3) ? 1 : 0);
    { float* tp;
      tp = hlnC; hlnC = hlnN; hlnN = tp;
      tp = ueC;  ueC  = ueN;  ueN  = tp;
      tp = ucC;  ucC  = ucN;  ucN  = tp;
      tp = vepC; vepC = vepN; vepN = tp;
      tp = vcpC; vcpC = vcpN; vcpN = tp;
      tp = xcur; xcur = xnext; xnext = tp;
    }
  }
}